// Round 8
// baseline (662.940 us; speedup 1.0000x reference)
//
#include <hip/hip_runtime.h>
#include <hip/hip_bf16.h>

// LightGCN on MI355X — round 17.
// R16 post-mortem: WIN (606.2us, new best). k_scat run-length fix confirmed;
// R9 spmm schedule restored (VGPR 20, 109us, occ 77%).
// R17 probe: is k_spmm BW- or MLP-bound? 0.17 gathers/ns/CU needs ~85
// outstanding/CU = ~3.5/wave; VGPR=20 recycling gives ~2-3. Change: TWO rows
// per wave with independent edge streams + accumulators (dual batch2<8>, no
// fences, no masking — unlike R12). Predict: latency-bound -> spmm 109->~90,
// total -> ~570; neutral -> spmm at pattern roofline, pivot to sort side.

#define DIM   64
#define FTHR  2048   // float sniff: >FTHR of 4096 words look bf16-packed
#define WTHR  512    // wide sniff:  >WTHR of 1024 odd words are zero -> int64
#define SHIFT 10
#define BSZ   (1 << SHIFT)     // 1024 dst rows per bucket
#define KMAX  1023             // scanB (1024 thr) handles up to 1023 buckets
#define CHUNK 16384            // edges per count/scat block
#define CTPB  512              // count/scat threads per block
#define STPB  512              // p2sort threads per block
#define SBT   1024             // scanB threads

__device__ __forceinline__ float bf2f(unsigned short u) {
    return __builtin_bit_cast(float, ((unsigned)u) << 16);
}
__device__ __forceinline__ unsigned short f2bf(float x) {
    return __builtin_bit_cast(unsigned short, __float2bfloat16(x));
}
__device__ __forceinline__ int idx_at(const void* a, long long i, int wide) {
    return wide ? (int)((const long long*)a)[i] : ((const int*)a)[i];
}
__device__ __forceinline__ int clampi(int v, int hi) {
    return v < 0 ? 0 : (v >= hi ? hi - 1 : v);
}

// flags: [0] ue float-kind [1] ie float-kind [2] eval float-kind
//        [3] edge idx wide [4] batch idx wide
__global__ void sniff_all(const unsigned* __restrict__ ue, const unsigned* __restrict__ ie,
                          const unsigned* __restrict__ eval, const unsigned* __restrict__ esrc,
                          const unsigned* __restrict__ users, int* __restrict__ flags) {
    int b = blockIdx.x, t = threadIdx.x;
    const unsigned* p = (b == 0) ? ue : (b == 1) ? ie : (b == 2) ? eval
                       : (b == 3) ? esrc : users;
    int cnt = 0;
    if (b < 3) {
        for (int i = t; i < 4096; i += 256) {
            unsigned e = (p[i] >> 7) & 0xffu;
            if (e >= 110u && e <= 135u) cnt++;
        }
    } else {
        for (int i = t; i < 1024; i += 256)
            if (p[2 * i + 1] == 0u) cnt++;
    }
    #pragma unroll
    for (int off = 32; off > 0; off >>= 1) cnt += __shfl_down(cnt, off, 64);
    if ((t & 63) == 0) atomicAdd(&flags[b], cnt);
}

// ---- stage inputs -> bf16 table S0 [N,64] ----
__global__ void stage_in(const void* __restrict__ ue, const void* __restrict__ ie,
                         ushort4* __restrict__ S, const int* __restrict__ flags,
                         int NU16, int N16) {
    int tid = blockIdx.x * blockDim.x + threadIdx.x;
    if (tid >= N16) return;
    bool user = tid < NU16;
    const void* src = user ? ue : ie;
    int fl  = user ? flags[0] : flags[1];
    int idx = user ? tid : tid - NU16;
    ushort4 o;
    if (fl > FTHR) {
        o = ((const ushort4*)src)[idx];
    } else {
        float4 v = ((const float4*)src)[idx];
        o.x = f2bf(v.x); o.y = f2bf(v.y); o.z = f2bf(v.z); o.w = f2bf(v.w);
    }
    S[tid] = o;
}

// ---- layer-0: out[slot] = input emb (f32) ----
__global__ void gather0(const void* __restrict__ ue, const void* __restrict__ ie,
                        const void* __restrict__ users, const void* __restrict__ items,
                        float* __restrict__ out, const int* __restrict__ flags,
                        int B, int NU, int NI) {
    int tid = blockIdx.x * blockDim.x + threadIdx.x;
    int r = tid >> 6, d = tid & 63;
    if (r >= 2 * B) return;
    int wide = flags[4] > WTHR;
    const void* src; long long row; int fl;
    if (r < B) { row = clampi(idx_at(users, r, wide), NU); src = ue; fl = flags[0]; }
    else       { row = clampi(idx_at(items, r - B, wide), NI); src = ie; fl = flags[1]; }
    float v;
    if (fl > FTHR) v = bf2f(((const unsigned short*)src)[row * 64 + d]);
    else           v = ((const float*)src)[row * 64 + d];
    out[tid] = v;
}

// ---- count: per-block LDS hist -> global atomic bucket totals ----
__global__ __launch_bounds__(CTPB) void k_count(const void* __restrict__ edst,
                        const int* __restrict__ flags,
                        int* __restrict__ btotal, int E, int N, int K) {
    __shared__ int h[KMAX + 1];
    int t = threadIdx.x;
    for (int i = t; i < K; i += CTPB) h[i] = 0;
    __syncthreads();
    int wide = flags[3] > WTHR;
    int base = blockIdx.x * CHUNK;
    int lim = min(base + CHUNK, E);
    for (int i = base + t; i < lim; i += CTPB) {
        int d = clampi(idx_at(edst, i, wide), N);
        atomicAdd(&h[d >> SHIFT], 1);
    }
    __syncthreads();
    for (int i = t; i < K; i += CTPB)
        if (h[i]) atomicAdd(&btotal[i], h[i]);
}

// ---- scanB: bucket starts + init global cursors (1 block, 1024 thr) ----
__global__ __launch_bounds__(SBT) void k_scanB(const int* __restrict__ btotal,
                        int* __restrict__ bucketStart, int* __restrict__ gcur,
                        int* __restrict__ rowstart, int K, int N) {
    __shared__ int sh[SBT];
    int t = threadIdx.x;
    int v = (t < K) ? btotal[t] : 0;
    sh[t] = v;
    for (int off = 1; off < SBT; off <<= 1) {
        __syncthreads();
        int y = (t >= off) ? sh[t - off] : 0;
        __syncthreads();
        sh[t] += y;
    }
    __syncthreads();
    if (t <= K) bucketStart[t] = sh[t] - v;   // exclusive (t=K: v=0 -> total)
    if (t < K)  gcur[t] = sh[t] - v;
    if (t == SBT - 1) rowstart[N] = sh[SBT - 1];  // total edge count
}

// ---- scat: reserve bucket ranges dynamically, LDS-cursor scatter ----
__global__ __launch_bounds__(CTPB) void k_scat(const void* __restrict__ esrc,
                       const void* __restrict__ edst,
                       const void* __restrict__ eval, const int* __restrict__ flags,
                       int* __restrict__ gcur, unsigned long long* __restrict__ TMP,
                       int E, int N, int K) {
    __shared__ int h[KMAX + 1];
    __shared__ int cur[KMAX + 1];
    int t = threadIdx.x;
    for (int i = t; i < K; i += CTPB) h[i] = 0;
    __syncthreads();
    int wide = flags[3] > WTHR;
    int evalbf = flags[2] > FTHR;
    int base = blockIdx.x * CHUNK;
    int lim = min(base + CHUNK, E);
    // pass A: chunk histogram (chunk stays L2-hot for pass B)
    for (int i = base + t; i < lim; i += CTPB) {
        int d = clampi(idx_at(edst, i, wide), N);
        atomicAdd(&h[d >> SHIFT], 1);
    }
    __syncthreads();
    // reserve contiguous ranges in each touched bucket
    for (int i = t; i < K; i += CTPB)
        if (h[i]) cur[i] = atomicAdd(&gcur[i], h[i]);
    __syncthreads();
    // pass B: scatter via LDS cursors (runs of ~56 edges/bucket = 448B)
    for (int i = base + t; i < lim; i += CTPB) {
        int d = clampi(idx_at(edst, i, wide), N);
        int s = clampi(idx_at(esrc, i, wide), N);
        unsigned short vb = evalbf ? ((const unsigned short*)eval)[i]
                                   : f2bf(((const float*)eval)[i]);
        int b = d >> SHIFT;
        unsigned dl = (unsigned)(d & (BSZ - 1));
        int slot = atomicAdd(&cur[b], 1);
        unsigned long long p = (unsigned long long)(unsigned)s
                             | (((unsigned long long)((dl << 16) | vb)) << 32);
        TMP[slot] = p;
    }
}

// ---- sort pass 2: in-bucket counting sort + rowstart (1 block/bucket, 512 thr)
__global__ __launch_bounds__(STPB) void k_p2sort(const unsigned long long* __restrict__ TMP,
                         const int* __restrict__ bucketStart,
                         int2* __restrict__ edges, int* __restrict__ rowstart,
                         int N) {
    __shared__ int hist[BSZ];
    __shared__ int wsum[STPB / 64];
    int b = blockIdx.x;
    int t = threadIdx.x;
    int span0 = bucketStart[b], span1 = bucketStart[b + 1];
    int rbase = b << SHIFT;
    int nrows = min(BSZ, N - rbase);
    for (int i = t; i < BSZ; i += STPB) hist[i] = 0;
    __syncthreads();
    for (int e = span0 + t; e < span1; e += STPB) {
        int dl = (int)((TMP[e] >> 48) & (BSZ - 1));
        atomicAdd(&hist[dl], 1);
    }
    __syncthreads();
    // block-wide exclusive prefix sum over BSZ entries, BSZ/STPB per thread
    const int PER = BSZ / STPB;   // 2
    int loc[PER];
    int s = 0;
    #pragma unroll
    for (int j = 0; j < PER; ++j) {
        int v = hist[t * PER + j];
        loc[j] = s;
        s += v;
    }
    int wid = t >> 6, lane = t & 63;
    int x = s;
    #pragma unroll
    for (int off = 1; off < 64; off <<= 1) {
        int y = __shfl_up(x, off, 64);
        if (lane >= off) x += y;
    }
    if (lane == 63) wsum[wid] = x;
    __syncthreads();
    int wbase = 0;
    #pragma unroll
    for (int w = 0; w < STPB / 64; ++w) wbase += (w < wid) ? wsum[w] : 0;
    int texcl = wbase + x - s;
    #pragma unroll
    for (int j = 0; j < PER; ++j) hist[t * PER + j] = texcl + loc[j];
    __syncthreads();
    // rowstart for this bucket's rows
    for (int r = t; r < nrows; r += STPB) rowstart[rbase + r] = span0 + hist[r];
    __syncthreads();
    // scatter to final sorted position (hist doubles as cursor)
    for (int e = span0 + t; e < span1; e += STPB) {
        unsigned long long p = TMP[e];
        int dl = (int)((p >> 48) & (BSZ - 1));
        unsigned vb = (unsigned)((p >> 32) & 0xffffu);
        int src = (int)(unsigned)p;
        int slot = span0 + atomicAdd(&hist[dl], 1);
        edges[slot] = make_int2(src, (int)(vb << 16));
    }
}

// ---- dual-row SpMM batch: two independent chains (MLP x2, no fences) ----
template <int U>
__device__ __forceinline__ void spmm_batch2(const unsigned short* __restrict__ Sin,
                                            const int2* __restrict__ edges,
                                            int k0, int k1, int lane,
                                            float& acc0, float& acc1) {
    int2 d0[U], d1[U];
    #pragma unroll
    for (int j = 0; j < U; ++j) { d0[j] = edges[k0 + j]; d1[j] = edges[k1 + j]; }
    float a0[U], a1[U];
    #pragma unroll
    for (int j = 0; j < U; ++j) {
        a0[j] = bf2f(Sin[(size_t)d0[j].x * 64 + lane]);
        a1[j] = bf2f(Sin[(size_t)d1[j].x * 64 + lane]);
    }
    #pragma unroll
    for (int j = 0; j < U; ++j) {
        acc0 += __int_as_float(d0[j].y) * a0[j];
        acc1 += __int_as_float(d1[j].y) * a1[j];
    }
}

// ---- single-row tail ladder — k_spmm's private copy ----
template <int U>
__device__ __forceinline__ void spmm_batchA(const unsigned short* __restrict__ Sin,
                                            const int2* __restrict__ edges,
                                            int k, int lane, float& acc) {
    int2 e[U];
    #pragma unroll
    for (int j = 0; j < U; ++j) e[j] = edges[k + j];
    float a[U];
    #pragma unroll
    for (int j = 0; j < U; ++j) a[j] = bf2f(Sin[(size_t)e[j].x * 64 + lane]);
    #pragma unroll
    for (int j = 0; j < U; ++j) acc += __int_as_float(e[j].y) * a[j];
}

__device__ __forceinline__ float spmm_tailA(const unsigned short* __restrict__ Sin,
                                            const int2* __restrict__ edges,
                                            int k, int end, int lane, float acc) {
    for (; k + 16 <= end; k += 16) spmm_batchA<16>(Sin, edges, k, lane, acc);
    if (k + 8 <= end) { spmm_batchA<8>(Sin, edges, k, lane, acc); k += 8; }
    if (k + 4 <= end) { spmm_batchA<4>(Sin, edges, k, lane, acc); k += 4; }
    if (k + 2 <= end) { spmm_batchA<2>(Sin, edges, k, lane, acc); k += 2; }
    if (k < end)      { spmm_batchA<1>(Sin, edges, k, lane, acc); }
    return acc;
}

// ---- full SpMM: one wave per TWO dst rows, lane = dim ----
__global__ void k_spmm(const unsigned short* __restrict__ Sin,
                       unsigned short* __restrict__ Sout,
                       const int* __restrict__ rowstart,
                       const int2* __restrict__ edges, int N) {
    int wp = (blockIdx.x * blockDim.x + threadIdx.x) >> 6;
    int lane = threadIdx.x & 63;
    int r0 = wp * 2, r1 = wp * 2 + 1;
    if (r0 >= N) return;
    bool has1 = r1 < N;
    int s0 = __builtin_amdgcn_readfirstlane(rowstart[r0]);
    int e0 = __builtin_amdgcn_readfirstlane(rowstart[r0 + 1]);
    int s1 = has1 ? __builtin_amdgcn_readfirstlane(rowstart[r1]) : 0;
    int e1 = has1 ? __builtin_amdgcn_readfirstlane(rowstart[r1 + 1]) : 0;
    float acc0 = 0.f, acc1 = 0.f;
    while (s0 + 8 <= e0 && s1 + 8 <= e1) {
        spmm_batch2<8>(Sin, edges, s0, s1, lane, acc0, acc1);
        s0 += 8; s1 += 8;
    }
    acc0 = spmm_tailA(Sin, edges, s0, e0, lane, acc0);
    acc1 = spmm_tailA(Sin, edges, s1, e1, lane, acc1);
    __builtin_nontemporal_store(f2bf(acc0), &Sout[(size_t)r0 * 64 + lane]);
    if (has1)
        __builtin_nontemporal_store(f2bf(acc1), &Sout[(size_t)r1 * 64 + lane]);
}

// ---- k_spmm_b's private copy of the body (codegen isolation) ----
template <int U>
__device__ __forceinline__ void spmm_batchB(const unsigned short* __restrict__ Sin,
                                            const int2* __restrict__ edges,
                                            int k, int lane, float& acc) {
    int2 e[U];
    #pragma unroll
    for (int j = 0; j < U; ++j) e[j] = edges[k + j];
    float a[U];
    #pragma unroll
    for (int j = 0; j < U; ++j) a[j] = bf2f(Sin[(size_t)e[j].x * 64 + lane]);
    #pragma unroll
    for (int j = 0; j < U; ++j) acc += __int_as_float(e[j].y) * a[j];
}

// ---- final layer fused: SpMM only at batch rows, accumulate f32 into out ----
__global__ void k_spmm_b(const unsigned short* __restrict__ Sin,
                         const void* __restrict__ users, const void* __restrict__ items,
                         const int* __restrict__ rowstart, const int2* __restrict__ edges,
                         float* __restrict__ out, const int* __restrict__ flags,
                         int B, int NU, int NI) {
    int tid = blockIdx.x * blockDim.x + threadIdx.x;
    int wid = tid >> 6, lane = threadIdx.x & 63;
    if (wid >= 2 * B) return;
    int wide = flags[4] > WTHR;
    int row;
    if (wid < B) row = clampi(idx_at(users, wid, wide), NU);
    else         row = NU + clampi(idx_at(items, wid - B, wide), NI);
    int start = __builtin_amdgcn_readfirstlane(rowstart[row]);
    int end   = __builtin_amdgcn_readfirstlane(rowstart[row + 1]);
    float acc = 0.f;
    int k = start;
    for (; k + 16 <= end; k += 16) spmm_batchB<16>(Sin, edges, k, lane, acc);
    if (k + 8 <= end) { spmm_batchB<8>(Sin, edges, k, lane, acc); k += 8; }
    if (k + 4 <= end) { spmm_batchB<4>(Sin, edges, k, lane, acc); k += 4; }
    if (k + 2 <= end) { spmm_batchB<2>(Sin, edges, k, lane, acc); k += 2; }
    if (k < end)      { spmm_batchB<1>(Sin, edges, k, lane, acc); }
    out[(size_t)wid * 64 + lane] += acc;
}

// ---- accumulate batch rows from bf16 layer table into d_out ----
__global__ void k_gacc(const unsigned short* __restrict__ S,
                       const void* __restrict__ users, const void* __restrict__ items,
                       float* __restrict__ out, const int* __restrict__ flags,
                       int B, int NU, int NI) {
    int tid = blockIdx.x * blockDim.x + threadIdx.x;
    int r = tid >> 6, d = tid & 63;
    if (r >= 2 * B) return;
    int wide = flags[4] > WTHR;
    long long row;
    if (r < B) row = clampi(idx_at(users, r, wide), NU);
    else       row = (long long)NU + clampi(idx_at(items, r - B, wide), NI);
    out[tid] += bf2f(S[row * 64 + d]);
}

// ---- epilogue: scale by 1/4 in place, compute scores ----
__global__ void epilogue(float* __restrict__ out, int B) {
    int tid = blockIdx.x * blockDim.x + threadIdx.x;
    int b = tid >> 6, d = tid & 63;
    if (b >= B) return;
    float u = out[tid] * 0.25f;
    float i = out[B * 64 + tid] * 0.25f;
    out[tid] = u;
    out[B * 64 + tid] = i;
    float p = u * i;
    #pragma unroll
    for (int off = 32; off > 0; off >>= 1) p += __shfl_down(p, off, 64);
    if (d == 0) out[2 * B * 64 + b] = p;
}

__global__ void diag_fill(float* __restrict__ out, int n, float marker) {
    int tid = blockIdx.x * blockDim.x + threadIdx.x;
    if (tid < n) out[tid] = marker;
}

extern "C" void kernel_launch(void* const* d_in, const int* in_sizes, int n_in,
                              void* d_out, int out_size, void* d_ws, size_t ws_size,
                              hipStream_t stream) {
    const void* ue    = d_in[0];
    const void* ie    = d_in[1];
    const void* esrc  = d_in[2];
    const void* edst  = d_in[3];
    const void* eval  = d_in[4];
    const void* users = d_in[5];
    const void* items = d_in[6];
    float* out = (float*)d_out;

    const int TPB = 256;
    if (n_in != 7) {
        diag_fill<<<(out_size + TPB - 1) / TPB, TPB, 0, stream>>>(out, out_size,
                                                                  3000.0f + 64.0f * n_in);
        return;
    }

    const int NU = in_sizes[0] / DIM;
    const int NI = in_sizes[1] / DIM;
    const int N  = NU + NI;
    const int E  = in_sizes[2];
    const int B  = in_sizes[5];
    const int K    = (N + BSZ - 1) >> SHIFT;
    const int NBLK = (E + CHUNK - 1) / CHUNK;

    const size_t sBytes   = (size_t)N * DIM * sizeof(unsigned short);
    const size_t tmpBytes = sBytes > (size_t)E * 8 ? sBytes : (size_t)E * 8;
    size_t off = 0;
    auto take = [&](size_t bytes) { size_t o = off; off += (bytes + 255) & ~255ull; return o; };
    char* base = (char*)d_ws;
    unsigned short* S0   = (unsigned short*)(base + take(sBytes));
    unsigned short* S1   = (unsigned short*)(base + take(tmpBytes));   // doubles as TMP
    int2*  edges   = (int2*)(base + take((size_t)E * 8));
    int*   btotal  = (int*)(base + take((KMAX + 1) * 4));
    int*   gcur    = (int*)(base + take((KMAX + 1) * 4));
    int*   bucketStart = (int*)(base + take((KMAX + 2) * 4));
    int*   rowstart    = (int*)(base + take((size_t)(N + 1) * 4));
    int*   flags   = (int*)(base + take(64));
    const size_t need = off;

    if (ws_size < need || K > KMAX) {
        diag_fill<<<(out_size + TPB - 1) / TPB, TPB, 0, stream>>>(out, out_size,
                                                                  1000.0f + (float)(ws_size >> 20));
        return;
    }

    const int N16 = N * 16, NU16 = NU * 16;
    dim3 gStage((N16 + TPB - 1) / TPB);
    dim3 gBatch((2 * B * 64 + TPB - 1) / TPB);
    dim3 gSpmm((((size_t)(N + 1) / 2) * 64 + TPB - 1) / TPB);
    dim3 gEpi((B * 64 + TPB - 1) / TPB);

    (void)hipMemsetAsync(flags, 0, 8 * sizeof(int), stream);
    (void)hipMemsetAsync(btotal, 0, (size_t)(K + 1) * sizeof(int), stream);

    sniff_all<<<5, 256, 0, stream>>>((const unsigned*)ue, (const unsigned*)ie,
                                     (const unsigned*)eval, (const unsigned*)esrc,
                                     (const unsigned*)users, flags);

    gather0<<<gBatch, TPB, 0, stream>>>(ue, ie, users, items, out, flags, B, NU, NI);
    stage_in<<<gStage, TPB, 0, stream>>>(ue, ie, (ushort4*)S0, flags, NU16, N16);

    // binned counting sort (once): count -> scan -> reserve+scatter -> in-bucket
    k_count<<<NBLK, CTPB, 0, stream>>>(edst, flags, btotal, E, N, K);
    k_scanB<<<1, SBT, 0, stream>>>(btotal, bucketStart, gcur, rowstart, K, N);
    k_scat<<<NBLK, CTPB, 0, stream>>>(esrc, edst, eval, flags, gcur,
                                      (unsigned long long*)S1, E, N, K);
    k_p2sort<<<K, STPB, 0, stream>>>((const unsigned long long*)S1, bucketStart,
                                     edges, rowstart, N);

    // layers 1,2: full SpMM + batch accumulate; layer 3: fused batch-row SpMM
    k_spmm<<<gSpmm, TPB, 0, stream>>>(S0, S1, rowstart, edges, N);
    k_gacc<<<gBatch, TPB, 0, stream>>>(S1, users, items, out, flags, B, NU, NI);
    k_spmm<<<gSpmm, TPB, 0, stream>>>(S1, S0, rowstart, edges, N);
    k_gacc<<<gBatch, TPB, 0, stream>>>(S0, users, items, out, flags, B, NU, NI);
    k_spmm_b<<<gBatch, TPB, 0, stream>>>(S0, users, items, rowstart, edges, out, flags,
                                         B, NU, NI);
    epilogue<<<gEpi, TPB, 0, stream>>>(out, B);
}

// Round 9
// 597.529 us; speedup vs baseline: 1.1095x; 1.1095x over previous
//
#include <hip/hip_runtime.h>
#include <hip/hip_bf16.h>

// LightGCN on MI355X — round 18.
// R17 post-mortem: dual-row spmm REGRESSED 109->138us. SGPR 80->64 reveals
// R16's fast schedule s_loads wave-uniform edge descriptors into SGPRs
// (why 16-edge batches fit in VGPR=20); dual-row overflowed scalar budget.
// spmm R16 body is the pattern optimum — frozen. R18: revert spmm + three
// small orthogonal cuts: (1) fuse gather0 into stage_in, (2) single memset
// (flags+btotal adjacent), (3) k_scat register-stash of d[] skips edst
// re-read in pass B. Predict total 663 -> ~595-605.

#define DIM   64
#define FTHR  2048   // float sniff: >FTHR of 4096 words look bf16-packed
#define WTHR  512    // wide sniff:  >WTHR of 1024 odd words are zero -> int64
#define SHIFT 10
#define BSZ   (1 << SHIFT)     // 1024 dst rows per bucket
#define KMAX  1023             // scanB (1024 thr) handles up to 1023 buckets
#define CHUNK 16384            // edges per count/scat block
#define CTPB  512              // count/scat threads per block
#define SPT   (CHUNK / CTPB)   // 32 edges per thread in count/scat
#define STPB  512              // p2sort threads per block
#define SBT   1024             // scanB threads

__device__ __forceinline__ float bf2f(unsigned short u) {
    return __builtin_bit_cast(float, ((unsigned)u) << 16);
}
__device__ __forceinline__ unsigned short f2bf(float x) {
    return __builtin_bit_cast(unsigned short, __float2bfloat16(x));
}
__device__ __forceinline__ int idx_at(const void* a, long long i, int wide) {
    return wide ? (int)((const long long*)a)[i] : ((const int*)a)[i];
}
__device__ __forceinline__ int clampi(int v, int hi) {
    return v < 0 ? 0 : (v >= hi ? hi - 1 : v);
}

// flags: [0] ue float-kind [1] ie float-kind [2] eval float-kind
//        [3] edge idx wide [4] batch idx wide
__global__ void sniff_all(const unsigned* __restrict__ ue, const unsigned* __restrict__ ie,
                          const unsigned* __restrict__ eval, const unsigned* __restrict__ esrc,
                          const unsigned* __restrict__ users, int* __restrict__ flags) {
    int b = blockIdx.x, t = threadIdx.x;
    const unsigned* p = (b == 0) ? ue : (b == 1) ? ie : (b == 2) ? eval
                       : (b == 3) ? esrc : users;
    int cnt = 0;
    if (b < 3) {
        for (int i = t; i < 4096; i += 256) {
            unsigned e = (p[i] >> 7) & 0xffu;
            if (e >= 110u && e <= 135u) cnt++;
        }
    } else {
        for (int i = t; i < 1024; i += 256)
            if (p[2 * i + 1] == 0u) cnt++;
    }
    #pragma unroll
    for (int off = 32; off > 0; off >>= 1) cnt += __shfl_down(cnt, off, 64);
    if ((t & 63) == 0) atomicAdd(&flags[b], cnt);
}

// ---- fused: stage inputs -> bf16 table S0 [N,64]  AND  layer-0 batch gather
__global__ void stage_gather(const void* __restrict__ ue, const void* __restrict__ ie,
                             const void* __restrict__ users, const void* __restrict__ items,
                             ushort4* __restrict__ S, float* __restrict__ out,
                             const int* __restrict__ flags,
                             int NU16, int N16, int B, int NU, int NI) {
    int tid = blockIdx.x * blockDim.x + threadIdx.x;
    if (tid < N16) {
        // stage: one ushort4 (4 bf16) per thread
        bool user = tid < NU16;
        const void* src = user ? ue : ie;
        int fl  = user ? flags[0] : flags[1];
        int idx = user ? tid : tid - NU16;
        ushort4 o;
        if (fl > FTHR) {
            o = ((const ushort4*)src)[idx];
        } else {
            float4 v = ((const float4*)src)[idx];
            o.x = f2bf(v.x); o.y = f2bf(v.y); o.z = f2bf(v.z); o.w = f2bf(v.w);
        }
        S[tid] = o;
    } else {
        // layer-0 gather: out[slot] = input emb (f32)
        int g = tid - N16;
        int r = g >> 6, d = g & 63;
        if (r >= 2 * B) return;
        int wide = flags[4] > WTHR;
        const void* src; long long row; int fl;
        if (r < B) { row = clampi(idx_at(users, r, wide), NU); src = ue; fl = flags[0]; }
        else       { row = clampi(idx_at(items, r - B, wide), NI); src = ie; fl = flags[1]; }
        float v;
        if (fl > FTHR) v = bf2f(((const unsigned short*)src)[row * 64 + d]);
        else           v = ((const float*)src)[row * 64 + d];
        out[g] = v;
    }
}

// ---- count: per-block LDS hist -> global atomic bucket totals ----
__global__ __launch_bounds__(CTPB) void k_count(const void* __restrict__ edst,
                        const int* __restrict__ flags,
                        int* __restrict__ btotal, int E, int N, int K) {
    __shared__ int h[KMAX + 1];
    int t = threadIdx.x;
    for (int i = t; i < K; i += CTPB) h[i] = 0;
    __syncthreads();
    int wide = flags[3] > WTHR;
    int base = blockIdx.x * CHUNK;
    int lim = min(base + CHUNK, E);
    for (int i = base + t; i < lim; i += CTPB) {
        int d = clampi(idx_at(edst, i, wide), N);
        atomicAdd(&h[d >> SHIFT], 1);
    }
    __syncthreads();
    for (int i = t; i < K; i += CTPB)
        if (h[i]) atomicAdd(&btotal[i], h[i]);
}

// ---- scanB: bucket starts + init global cursors (1 block, 1024 thr) ----
__global__ __launch_bounds__(SBT) void k_scanB(const int* __restrict__ btotal,
                        int* __restrict__ bucketStart, int* __restrict__ gcur,
                        int* __restrict__ rowstart, int K, int N) {
    __shared__ int sh[SBT];
    int t = threadIdx.x;
    int v = (t < K) ? btotal[t] : 0;
    sh[t] = v;
    for (int off = 1; off < SBT; off <<= 1) {
        __syncthreads();
        int y = (t >= off) ? sh[t - off] : 0;
        __syncthreads();
        sh[t] += y;
    }
    __syncthreads();
    if (t <= K) bucketStart[t] = sh[t] - v;   // exclusive (t=K: v=0 -> total)
    if (t < K)  gcur[t] = sh[t] - v;
    if (t == SBT - 1) rowstart[N] = sh[SBT - 1];  // total edge count
}

// ---- scat: reserve bucket ranges dynamically, LDS-cursor scatter ----
// pass A stashes clamped d in registers (SPT=32/thread) so pass B skips edst.
__global__ __launch_bounds__(CTPB) void k_scat(const void* __restrict__ esrc,
                       const void* __restrict__ edst,
                       const void* __restrict__ eval, const int* __restrict__ flags,
                       int* __restrict__ gcur, unsigned long long* __restrict__ TMP,
                       int E, int N, int K) {
    __shared__ int h[KMAX + 1];
    __shared__ int cur[KMAX + 1];
    int t = threadIdx.x;
    for (int i = t; i < K; i += CTPB) h[i] = 0;
    __syncthreads();
    int wide = flags[3] > WTHR;
    int evalbf = flags[2] > FTHR;
    int base = blockIdx.x * CHUNK;
    int lim = min(base + CHUNK, E);
    // pass A: chunk histogram; stash d in registers (static indexing)
    int dstash[SPT];
    #pragma unroll
    for (int j = 0; j < SPT; ++j) {
        int i = base + t + j * CTPB;
        int d = 0;
        if (i < lim) {
            d = clampi(idx_at(edst, i, wide), N);
            atomicAdd(&h[d >> SHIFT], 1);
        }
        dstash[j] = d;
    }
    __syncthreads();
    // reserve contiguous ranges in each touched bucket
    for (int i = t; i < K; i += CTPB)
        if (h[i]) cur[i] = atomicAdd(&gcur[i], h[i]);
    __syncthreads();
    // pass B: scatter via LDS cursors (runs of ~56 edges/bucket = 448B)
    #pragma unroll
    for (int j = 0; j < SPT; ++j) {
        int i = base + t + j * CTPB;
        if (i >= lim) continue;
        int d = dstash[j];
        int s = clampi(idx_at(esrc, i, wide), N);
        unsigned short vb = evalbf ? ((const unsigned short*)eval)[i]
                                   : f2bf(((const float*)eval)[i]);
        int b = d >> SHIFT;
        unsigned dl = (unsigned)(d & (BSZ - 1));
        int slot = atomicAdd(&cur[b], 1);
        unsigned long long p = (unsigned long long)(unsigned)s
                             | (((unsigned long long)((dl << 16) | vb)) << 32);
        TMP[slot] = p;
    }
}

// ---- sort pass 2: in-bucket counting sort + rowstart (1 block/bucket, 512 thr)
__global__ __launch_bounds__(STPB) void k_p2sort(const unsigned long long* __restrict__ TMP,
                         const int* __restrict__ bucketStart,
                         int2* __restrict__ edges, int* __restrict__ rowstart,
                         int N) {
    __shared__ int hist[BSZ];
    __shared__ int wsum[STPB / 64];
    int b = blockIdx.x;
    int t = threadIdx.x;
    int span0 = bucketStart[b], span1 = bucketStart[b + 1];
    int rbase = b << SHIFT;
    int nrows = min(BSZ, N - rbase);
    for (int i = t; i < BSZ; i += STPB) hist[i] = 0;
    __syncthreads();
    for (int e = span0 + t; e < span1; e += STPB) {
        int dl = (int)((TMP[e] >> 48) & (BSZ - 1));
        atomicAdd(&hist[dl], 1);
    }
    __syncthreads();
    // block-wide exclusive prefix sum over BSZ entries, BSZ/STPB per thread
    const int PER = BSZ / STPB;   // 2
    int loc[PER];
    int s = 0;
    #pragma unroll
    for (int j = 0; j < PER; ++j) {
        int v = hist[t * PER + j];
        loc[j] = s;
        s += v;
    }
    int wid = t >> 6, lane = t & 63;
    int x = s;
    #pragma unroll
    for (int off = 1; off < 64; off <<= 1) {
        int y = __shfl_up(x, off, 64);
        if (lane >= off) x += y;
    }
    if (lane == 63) wsum[wid] = x;
    __syncthreads();
    int wbase = 0;
    #pragma unroll
    for (int w = 0; w < STPB / 64; ++w) wbase += (w < wid) ? wsum[w] : 0;
    int texcl = wbase + x - s;
    #pragma unroll
    for (int j = 0; j < PER; ++j) hist[t * PER + j] = texcl + loc[j];
    __syncthreads();
    // rowstart for this bucket's rows
    for (int r = t; r < nrows; r += STPB) rowstart[rbase + r] = span0 + hist[r];
    __syncthreads();
    // scatter to final sorted position (hist doubles as cursor)
    for (int e = span0 + t; e < span1; e += STPB) {
        unsigned long long p = TMP[e];
        int dl = (int)((p >> 48) & (BSZ - 1));
        unsigned vb = (unsigned)((p >> 32) & 0xffffu);
        int src = (int)(unsigned)p;
        int slot = span0 + atomicAdd(&hist[dl], 1);
        edges[slot] = make_int2(src, (int)(vb << 16));
    }
}

// ---- atomic-free SpMM body — k_spmm's private copy (R16 frozen form) ----
template <int U>
__device__ __forceinline__ void spmm_batchA(const unsigned short* __restrict__ Sin,
                                            const int2* __restrict__ edges,
                                            int k, int lane, float& acc) {
    int2 e[U];
    #pragma unroll
    for (int j = 0; j < U; ++j) e[j] = edges[k + j];
    float a[U];
    #pragma unroll
    for (int j = 0; j < U; ++j) a[j] = bf2f(Sin[(size_t)e[j].x * 64 + lane]);
    #pragma unroll
    for (int j = 0; j < U; ++j) acc += __int_as_float(e[j].y) * a[j];
}

// ---- full SpMM: one wave per dst row, lane = dim ----
__global__ void k_spmm(const unsigned short* __restrict__ Sin,
                       unsigned short* __restrict__ Sout,
                       const int* __restrict__ rowstart,
                       const int2* __restrict__ edges, int N) {
    int wid = (blockIdx.x * blockDim.x + threadIdx.x) >> 6;
    int lane = threadIdx.x & 63;
    if (wid >= N) return;
    int start = __builtin_amdgcn_readfirstlane(rowstart[wid]);
    int end   = __builtin_amdgcn_readfirstlane(rowstart[wid + 1]);
    float acc = 0.f;
    int k = start;
    for (; k + 16 <= end; k += 16) spmm_batchA<16>(Sin, edges, k, lane, acc);
    if (k + 8 <= end) { spmm_batchA<8>(Sin, edges, k, lane, acc); k += 8; }
    if (k + 4 <= end) { spmm_batchA<4>(Sin, edges, k, lane, acc); k += 4; }
    if (k + 2 <= end) { spmm_batchA<2>(Sin, edges, k, lane, acc); k += 2; }
    if (k < end)      { spmm_batchA<1>(Sin, edges, k, lane, acc); }
    __builtin_nontemporal_store(f2bf(acc), &Sout[(size_t)wid * 64 + lane]);
}

// ---- k_spmm_b's private copy of the body (codegen isolation) ----
template <int U>
__device__ __forceinline__ void spmm_batchB(const unsigned short* __restrict__ Sin,
                                            const int2* __restrict__ edges,
                                            int k, int lane, float& acc) {
    int2 e[U];
    #pragma unroll
    for (int j = 0; j < U; ++j) e[j] = edges[k + j];
    float a[U];
    #pragma unroll
    for (int j = 0; j < U; ++j) a[j] = bf2f(Sin[(size_t)e[j].x * 64 + lane]);
    #pragma unroll
    for (int j = 0; j < U; ++j) acc += __int_as_float(e[j].y) * a[j];
}

// ---- final layer fused: SpMM only at batch rows, accumulate f32 into out ----
__global__ void k_spmm_b(const unsigned short* __restrict__ Sin,
                         const void* __restrict__ users, const void* __restrict__ items,
                         const int* __restrict__ rowstart, const int2* __restrict__ edges,
                         float* __restrict__ out, const int* __restrict__ flags,
                         int B, int NU, int NI) {
    int tid = blockIdx.x * blockDim.x + threadIdx.x;
    int wid = tid >> 6, lane = threadIdx.x & 63;
    if (wid >= 2 * B) return;
    int wide = flags[4] > WTHR;
    int row;
    if (wid < B) row = clampi(idx_at(users, wid, wide), NU);
    else         row = NU + clampi(idx_at(items, wid - B, wide), NI);
    int start = __builtin_amdgcn_readfirstlane(rowstart[row]);
    int end   = __builtin_amdgcn_readfirstlane(rowstart[row + 1]);
    float acc = 0.f;
    int k = start;
    for (; k + 16 <= end; k += 16) spmm_batchB<16>(Sin, edges, k, lane, acc);
    if (k + 8 <= end) { spmm_batchB<8>(Sin, edges, k, lane, acc); k += 8; }
    if (k + 4 <= end) { spmm_batchB<4>(Sin, edges, k, lane, acc); k += 4; }
    if (k + 2 <= end) { spmm_batchB<2>(Sin, edges, k, lane, acc); k += 2; }
    if (k < end)      { spmm_batchB<1>(Sin, edges, k, lane, acc); }
    out[(size_t)wid * 64 + lane] += acc;
}

// ---- accumulate batch rows from bf16 layer table into d_out ----
__global__ void k_gacc(const unsigned short* __restrict__ S,
                       const void* __restrict__ users, const void* __restrict__ items,
                       float* __restrict__ out, const int* __restrict__ flags,
                       int B, int NU, int NI) {
    int tid = blockIdx.x * blockDim.x + threadIdx.x;
    int r = tid >> 6, d = tid & 63;
    if (r >= 2 * B) return;
    int wide = flags[4] > WTHR;
    long long row;
    if (r < B) row = clampi(idx_at(users, r, wide), NU);
    else       row = (long long)NU + clampi(idx_at(items, r - B, wide), NI);
    out[tid] += bf2f(S[row * 64 + d]);
}

// ---- epilogue: scale by 1/4 in place, compute scores ----
__global__ void epilogue(float* __restrict__ out, int B) {
    int tid = blockIdx.x * blockDim.x + threadIdx.x;
    int b = tid >> 6, d = tid & 63;
    if (b >= B) return;
    float u = out[tid] * 0.25f;
    float i = out[B * 64 + tid] * 0.25f;
    out[tid] = u;
    out[B * 64 + tid] = i;
    float p = u * i;
    #pragma unroll
    for (int off = 32; off > 0; off >>= 1) p += __shfl_down(p, off, 64);
    if (d == 0) out[2 * B * 64 + b] = p;
}

__global__ void diag_fill(float* __restrict__ out, int n, float marker) {
    int tid = blockIdx.x * blockDim.x + threadIdx.x;
    if (tid < n) out[tid] = marker;
}

extern "C" void kernel_launch(void* const* d_in, const int* in_sizes, int n_in,
                              void* d_out, int out_size, void* d_ws, size_t ws_size,
                              hipStream_t stream) {
    const void* ue    = d_in[0];
    const void* ie    = d_in[1];
    const void* esrc  = d_in[2];
    const void* edst  = d_in[3];
    const void* eval  = d_in[4];
    const void* users = d_in[5];
    const void* items = d_in[6];
    float* out = (float*)d_out;

    const int TPB = 256;
    if (n_in != 7) {
        diag_fill<<<(out_size + TPB - 1) / TPB, TPB, 0, stream>>>(out, out_size,
                                                                  3000.0f + 64.0f * n_in);
        return;
    }

    const int NU = in_sizes[0] / DIM;
    const int NI = in_sizes[1] / DIM;
    const int N  = NU + NI;
    const int E  = in_sizes[2];
    const int B  = in_sizes[5];
    const int K    = (N + BSZ - 1) >> SHIFT;
    const int NBLK = (E + CHUNK - 1) / CHUNK;

    const size_t sBytes   = (size_t)N * DIM * sizeof(unsigned short);
    const size_t tmpBytes = sBytes > (size_t)E * 8 ? sBytes : (size_t)E * 8;
    size_t off = 0;
    auto take = [&](size_t bytes) { size_t o = off; off += (bytes + 255) & ~255ull; return o; };
    char* base = (char*)d_ws;
    unsigned short* S0   = (unsigned short*)(base + take(sBytes));
    unsigned short* S1   = (unsigned short*)(base + take(tmpBytes));   // doubles as TMP
    int2*  edges   = (int2*)(base + take((size_t)E * 8));
    int*   flags   = (int*)(base + take(64));            // flags and btotal adjacent:
    int*   btotal  = (int*)(base + take((KMAX + 1) * 4)); //  one memset covers both
    int*   gcur    = (int*)(base + take((KMAX + 1) * 4));
    int*   bucketStart = (int*)(base + take((KMAX + 2) * 4));
    int*   rowstart    = (int*)(base + take((size_t)(N + 1) * 4));
    const size_t need = off;

    if (ws_size < need || K > KMAX) {
        diag_fill<<<(out_size + TPB - 1) / TPB, TPB, 0, stream>>>(out, out_size,
                                                                  1000.0f + (float)(ws_size >> 20));
        return;
    }

    const int N16 = N * 16, NU16 = NU * 16;
    dim3 gSG(((size_t)N16 + 2 * B * 64 + TPB - 1) / TPB);
    dim3 gBatch((2 * B * 64 + TPB - 1) / TPB);
    dim3 gSpmm(((size_t)N * 64 + TPB - 1) / TPB);
    dim3 gEpi((B * 64 + TPB - 1) / TPB);

    // flags (256B-aligned slot) + btotal are contiguous: single memset
    (void)hipMemsetAsync(flags, 0, 256 + (size_t)(K + 1) * sizeof(int), stream);

    sniff_all<<<5, 256, 0, stream>>>((const unsigned*)ue, (const unsigned*)ie,
                                     (const unsigned*)eval, (const unsigned*)esrc,
                                     (const unsigned*)users, flags);

    stage_gather<<<gSG, TPB, 0, stream>>>(ue, ie, users, items, (ushort4*)S0, out,
                                          flags, NU16, N16, B, NU, NI);

    // binned counting sort (once): count -> scan -> reserve+scatter -> in-bucket
    k_count<<<NBLK, CTPB, 0, stream>>>(edst, flags, btotal, E, N, K);
    k_scanB<<<1, SBT, 0, stream>>>(btotal, bucketStart, gcur, rowstart, K, N);
    k_scat<<<NBLK, CTPB, 0, stream>>>(esrc, edst, eval, flags, gcur,
                                      (unsigned long long*)S1, E, N, K);
    k_p2sort<<<K, STPB, 0, stream>>>((const unsigned long long*)S1, bucketStart,
                                     edges, rowstart, N);

    // layers 1,2: full SpMM + batch accumulate; layer 3: fused batch-row SpMM
    k_spmm<<<gSpmm, TPB, 0, stream>>>(S0, S1, rowstart, edges, N);
    k_gacc<<<gBatch, TPB, 0, stream>>>(S1, users, items, out, flags, B, NU, NI);
    k_spmm<<<gSpmm, TPB, 0, stream>>>(S1, S0, rowstart, edges, N);
    k_gacc<<<gBatch, TPB, 0, stream>>>(S0, users, items, out, flags, B, NU, NI);
    k_spmm_b<<<gBatch, TPB, 0, stream>>>(S0, users, items, rowstart, edges, out, flags,
                                         B, NU, NI);
    epilogue<<<gEpi, TPB, 0, stream>>>(out, B);
}